// Round 6
// baseline (342.123 us; speedup 1.0000x reference)
//
#include <hip/hip_runtime.h>

typedef __attribute__((ext_vector_type(4))) float f32x4;
typedef __attribute__((ext_vector_type(8))) short bf16x8;

__device__ __forceinline__ unsigned short f2bf(float f) {
  unsigned int u = __builtin_bit_cast(unsigned int, f);
  u += 0x7FFFu + ((u >> 16) & 1u);   // RTNE
  return (unsigned short)(u >> 16);
}

// ---- K0a: P[b][h] = b_attn[h] + dot(W_attn[h, 0:512], hidden[b, :])
__global__ __launch_bounds__(256) void k_prep_p(
    const float* __restrict__ hidden, const float* __restrict__ W,
    const float* __restrict__ bias, float* __restrict__ P) {
  __shared__ float hsh[512];
  const int b = blockIdx.x;
  for (int i = threadIdx.x; i < 512; i += 256) hsh[i] = hidden[b * 512 + i];
  __syncthreads();
  for (int h = threadIdx.x; h < 512; h += 256) {
    const float* wr = W + (long)h * 1536;
    float s = 0.f;
#pragma unroll 4
    for (int f = 0; f < 512; f += 4) {
      float4 wv = *reinterpret_cast<const float4*>(wr + f);
      s += wv.x * hsh[f] + wv.y * hsh[f + 1] + wv.z * hsh[f + 2] + wv.w * hsh[f + 3];
    }
    P[b * 512 + h] = bias[h] + s;
  }
}

// ---- K0b: W2t[kb][h][kk] = bf16(W_attn[h][512 + kb*32 + kk]),  kb<32, h<512, kk<32
__global__ __launch_bounds__(256) void k_prep_w(
    const float* __restrict__ W, unsigned short* __restrict__ W2t) {
  const int id = blockIdx.x * 256 + threadIdx.x;  // 65536 threads, 8 elems each
  const int kk8 = (id & 3) * 8;
  const int h = (id >> 2) & 511;
  const int kb = id >> 11;
  const float* src = W + (long)h * 1536 + 512 + kb * 32 + kk8;
  float4 a = *reinterpret_cast<const float4*>(src);
  float4 c = *reinterpret_cast<const float4*>(src + 4);
  union { unsigned short u[8]; bf16x8 v; } o;
  o.u[0] = f2bf(a.x); o.u[1] = f2bf(a.y); o.u[2] = f2bf(a.z); o.u[3] = f2bf(a.w);
  o.u[4] = f2bf(c.x); o.u[5] = f2bf(c.y); o.u[6] = f2bf(c.z); o.u[7] = f2bf(c.w);
  *reinterpret_cast<bf16x8*>(W2t + (long)kb * 16384 + h * 32 + kk8) = o.v;
}

// ---- K1: fused GEMM + tanh + v-reduce -> logits (complete, no partials)
// 1024 blocks x 512 thr = 8 independent waves. Wave w: 64 rows x cols [w*64,w*64+64).
// Block covers ALL 512 h-cols of its 64 rows -> enc read exactly once from HBM.
// No LDS, no barriers in K-loop. Explicit 2-deep register ping-pong for A (HBM)
// and B (L2-resident W2t): loads for kb+2 issued immediately after buf consumed,
// so the compiler emits counted vmcnt waits and the load pipe never drains.
__global__ __launch_bounds__(512, 2) void k_main(
    const float* __restrict__ enc, const short* __restrict__ W2t,
    const float* __restrict__ P, const float* __restrict__ v,
    float* __restrict__ logits) {
  __shared__ float attred[64][8];

  const int tid = threadIdx.x;
  const int lane = tid & 63;
  const int w = tid >> 6;               // 0..7: col panel [w*64, w*64+64)
  const int hl = lane & 15, kg = lane >> 4;
  const long rowbase = (long)blockIdx.x * 64;
  const int b = (int)(rowbase >> 12);   // 64 | 4096

  // A: frag mi -> rows rowbase+mi*16+hl, k chunk kg*8 (+ kb*32 per iter)
  const float* ap[4];
#pragma unroll
  for (int mi = 0; mi < 4; ++mi)
    ap[mi] = enc + (rowbase + mi * 16 + hl) * 1024 + kg * 8;
  // B: h = w*64 + ni*16 + hl; elem = kb*16384 + h*32 + kg*8
  const short* bp = W2t + (w * 64 + hl) * 32 + kg * 8;

  f32x4 acc[4][4];
#pragma unroll
  for (int mi = 0; mi < 4; ++mi)
#pragma unroll
    for (int ni = 0; ni < 4; ++ni) acc[mi][ni] = (f32x4){0.f, 0.f, 0.f, 0.f};

  // 2-deep ping-pong stages (all indices literal under #pragma unroll)
  f32x4 As[2][4][2];    // [buf][mi][half]
  bf16x8 Bs[2][4];      // [buf][ni]

#define LOAD_STAGE(PB, KB)                                                     \
  {                                                                            \
    const int _ko = (KB) * 32;                                                 \
    _Pragma("unroll") for (int mi = 0; mi < 4; ++mi) {                         \
      As[PB][mi][0] = *reinterpret_cast<const f32x4*>(ap[mi] + _ko);           \
      As[PB][mi][1] = *reinterpret_cast<const f32x4*>(ap[mi] + _ko + 4);       \
    }                                                                          \
    const short* _bk = bp + (KB) * 16384;                                      \
    _Pragma("unroll") for (int ni = 0; ni < 4; ++ni)                           \
        Bs[PB][ni] = *reinterpret_cast<const bf16x8*>(_bk + ni * 512);         \
  }

#define COMPUTE_STAGE(PB)                                                      \
  {                                                                            \
    _Pragma("unroll") for (int mi = 0; mi < 4; ++mi) {                         \
      f32x4 lo = As[PB][mi][0], hi = As[PB][mi][1];                            \
      union { __bf16 h[8]; bf16x8 s; } u;                                      \
      u.h[0] = (__bf16)lo[0]; u.h[1] = (__bf16)lo[1];                          \
      u.h[2] = (__bf16)lo[2]; u.h[3] = (__bf16)lo[3];                          \
      u.h[4] = (__bf16)hi[0]; u.h[5] = (__bf16)hi[1];                          \
      u.h[6] = (__bf16)hi[2]; u.h[7] = (__bf16)hi[3];                          \
      bf16x8 af = u.s;                                                         \
      _Pragma("unroll") for (int ni = 0; ni < 4; ++ni)                         \
          acc[mi][ni] = __builtin_amdgcn_mfma_f32_16x16x32_bf16(               \
              af, Bs[PB][ni], acc[mi][ni], 0, 0, 0);                           \
    }                                                                          \
  }

  LOAD_STAGE(0, 0)
  LOAD_STAGE(1, 1)
  for (int kb = 0; kb < 32; kb += 2) {
    COMPUTE_STAGE(0)
    if (kb + 2 < 32) LOAD_STAGE(0, kb + 2)
    COMPUTE_STAGE(1)
    if (kb + 3 < 32) LOAD_STAGE(1, kb + 3)
  }
#undef LOAD_STAGE
#undef COMPUTE_STAGE

  // epilogue: x = acc + P[b][h]; part += v[h]*tanh(x); reduce over hl lanes
  float part[4][4];
#pragma unroll
  for (int mi = 0; mi < 4; ++mi)
#pragma unroll
    for (int r = 0; r < 4; ++r) part[mi][r] = 0.f;

#pragma unroll
  for (int ni = 0; ni < 4; ++ni) {
    const int h = w * 64 + ni * 16 + hl;
    const float ph = P[b * 512 + h];
    const float vh = v[h];
#pragma unroll
    for (int mi = 0; mi < 4; ++mi)
#pragma unroll
      for (int r = 0; r < 4; ++r) {
        float x = acc[mi][ni][r] + ph;
        float e = __expf(2.f * x);
        part[mi][r] += vh * (1.f - 2.f * __frcp_rn(e + 1.f));
      }
  }
#pragma unroll
  for (int off = 1; off < 16; off <<= 1)
#pragma unroll
    for (int mi = 0; mi < 4; ++mi)
#pragma unroll
      for (int r = 0; r < 4; ++r)
        part[mi][r] += __shfl_xor(part[mi][r], off, 16);

  if (hl == 0) {
#pragma unroll
    for (int mi = 0; mi < 4; ++mi)
#pragma unroll
      for (int r = 0; r < 4; ++r)
        attred[mi * 16 + kg * 4 + r][w] = part[mi][r];
  }
  __syncthreads();
  if (tid < 64) {
    const float* a = attred[tid];
    logits[rowbase + tid] = ((a[0] + a[1]) + (a[2] + a[3])) +
                            ((a[4] + a[5]) + (a[6] + a[7]));
  }
}

// ---- K2: softmax over S=4096 per batch row
__global__ __launch_bounds__(256) void k_softmax(
    const float* __restrict__ logits, float* __restrict__ out) {
  const int b = blockIdx.x;
  const int t = threadIdx.x;
  const int wid = t >> 6, lane = t & 63;
  const float* L = logits + b * 4096;
  __shared__ float rmax[4], rsum[4];
  float lv[16];
  float m = -1e30f;
#pragma unroll
  for (int i = 0; i < 16; ++i) {
    lv[i] = L[t + i * 256];
    m = fmaxf(m, lv[i]);
  }
#pragma unroll
  for (int off = 32; off >= 1; off >>= 1) m = fmaxf(m, __shfl_xor(m, off));
  if (lane == 0) rmax[wid] = m;
  __syncthreads();
  m = fmaxf(fmaxf(rmax[0], rmax[1]), fmaxf(rmax[2], rmax[3]));
  float s = 0.f;
#pragma unroll
  for (int i = 0; i < 16; ++i) {
    lv[i] = __expf(lv[i] - m);
    s += lv[i];
  }
#pragma unroll
  for (int off = 32; off >= 1; off >>= 1) s += __shfl_xor(s, off);
  if (lane == 0) rsum[wid] = s;
  __syncthreads();
  s = rsum[0] + rsum[1] + rsum[2] + rsum[3];
  float inv = 1.0f / s;
#pragma unroll
  for (int i = 0; i < 16; ++i) out[b * 4096 + t + i * 256] = lv[i] * inv;
}

extern "C" void kernel_launch(void* const* d_in, const int* in_sizes, int n_in,
                              void* d_out, int out_size, void* d_ws, size_t ws_size,
                              hipStream_t stream) {
  const float* hidden = (const float*)d_in[0];   // [16,512]
  const float* enc    = (const float*)d_in[1];   // [16,4096,1024]
  const float* W      = (const float*)d_in[2];   // [512,1536]
  const float* bias   = (const float*)d_in[3];   // [512]
  const float* v      = (const float*)d_in[4];   // [512]
  float* out = (float*)d_out;                    // [16,4096]

  char* ws = (char*)d_ws;
  float* P = (float*)ws;                                       // 32 KB
  unsigned short* W2t = (unsigned short*)(ws + 32768);         // 1 MB
  float* logits = (float*)(ws + 32768 + 1048576);              // 256 KB

  k_prep_p<<<16, 256, 0, stream>>>(hidden, W, bias, P);
  k_prep_w<<<256, 256, 0, stream>>>(W, W2t);
  k_main<<<1024, 512, 0, stream>>>(enc, (const short*)W2t, P, v, logits);
  k_softmax<<<16, 256, 0, stream>>>(logits, out);
}

// Round 7
// 173.373 us; speedup vs baseline: 1.9733x; 1.9733x over previous
//
#include <hip/hip_runtime.h>

typedef __attribute__((ext_vector_type(4))) float f32x4;
typedef __attribute__((ext_vector_type(8))) short bf16x8;

typedef const __attribute__((address_space(1))) void* gptr_t;
typedef __attribute__((address_space(3))) void* lptr_t;
#define GLS16(g, l) __builtin_amdgcn_global_load_lds((gptr_t)(g), (lptr_t)(l), 16, 0, 0)
#define MEMBAR() asm volatile("" ::: "memory")

__device__ __forceinline__ unsigned short f2bf(float f) {
  unsigned int u = __builtin_bit_cast(unsigned int, f);
  u += 0x7FFFu + ((u >> 16) & 1u);   // RTNE
  return (unsigned short)(u >> 16);
}

// ---- K0a: P[b][h] = b_attn[h] + dot(W_attn[h, 0:512], hidden[b, :])
__global__ __launch_bounds__(256) void k_prep_p(
    const float* __restrict__ hidden, const float* __restrict__ W,
    const float* __restrict__ bias, float* __restrict__ P) {
  __shared__ float hsh[512];
  const int b = blockIdx.x;
  for (int i = threadIdx.x; i < 512; i += 256) hsh[i] = hidden[b * 512 + i];
  __syncthreads();
  for (int h = threadIdx.x; h < 512; h += 256) {
    const float* wr = W + (long)h * 1536;
    float s = 0.f;
#pragma unroll 4
    for (int f = 0; f < 512; f += 4) {
      float4 wv = *reinterpret_cast<const float4*>(wr + f);
      s += wv.x * hsh[f] + wv.y * hsh[f + 1] + wv.z * hsh[f + 2] + wv.w * hsh[f + 3];
    }
    P[b * 512 + h] = bias[h] + s;
  }
}

// ---- K0b: W2t[kb][h][kk] = bf16(W_attn[h][512 + kb*32 + kk]),  kb<32, h<512, kk<32
__global__ __launch_bounds__(256) void k_prep_w(
    const float* __restrict__ W, unsigned short* __restrict__ W2t) {
  const int id = blockIdx.x * 256 + threadIdx.x;  // 65536 threads, 8 elems each
  const int kk8 = (id & 3) * 8;
  const int h = (id >> 2) & 511;
  const int kb = id >> 11;
  const float* src = W + (long)h * 1536 + 512 + kb * 32 + kk8;
  float4 a = *reinterpret_cast<const float4*>(src);
  float4 c = *reinterpret_cast<const float4*>(src + 4);
  union { unsigned short u[8]; bf16x8 v; } o;
  o.u[0] = f2bf(a.x); o.u[1] = f2bf(a.y); o.u[2] = f2bf(a.z); o.u[3] = f2bf(a.w);
  o.u[4] = f2bf(c.x); o.u[5] = f2bf(c.y); o.u[6] = f2bf(c.z); o.u[7] = f2bf(c.w);
  *reinterpret_cast<bf16x8*>(W2t + (long)kb * 16384 + h * 32 + kk8) = o.v;
}

// ---- K1: fused GEMM + tanh + v-reduce -> logits partials
// 2048 blocks = 512 mtiles x 4 ntiles; 256 thr = 4 waves (2M x 2N), wave 64x64.
// BM=128 BN=128 BK=32. Depth-2 GLS pipeline: 4 LDS buffers, GLS(j+2) issued at
// iter j, counted s_waitcnt vmcnt(12) (never a drain), raw s_barrier AFTER the
// wait so all waves' GLS(j) are complete before buf j is read.
// Per-iter vmem issue order: B(j+1) regs, then GLS(j+2)  => wait-set {GLS(j),
// B(j)} is exactly the 8 oldest of 20 outstanding.
__global__ __launch_bounds__(256, 2) void k_main(
    const float* __restrict__ enc, const short* __restrict__ W2t,
    const float* __restrict__ P, const float* __restrict__ v,
    float* __restrict__ logits_part) {
  __shared__ float As[4][4096];        // 4 bufs x (128 rows x 32 k) f32 = 64 KB
  float (*attred)[2] = reinterpret_cast<float (*)[2]>(&As[0][0]);  // aliased

  const int tid = threadIdx.x;
  const int lane = tid & 63;
  const int w = tid >> 6;               // 4 waves
  const int wr = w >> 1, wc = w & 1;    // 2M x 2N
  const int hl = lane & 15, kg = lane >> 4;

  // XCD swizzle: 4 ntile-sharers of an mtile adjacent on one XCD (bijective)
  const int bid = blockIdx.x;
  const int xcd = bid & 7, idx = bid >> 3;        // idx 0..255
  const int mtile = xcd * 64 + (idx >> 2);        // 0..511
  const int ntile = idx & 3;
  const long rowbase = (long)mtile * 128;
  const int colbase = ntile * 128;
  const int b = (int)(rowbase >> 12);             // 128 | 4096

  // A staging: per wave 4 GLS, each 8 rows x 32 k (1 KB). LDS linear; global
  // source chunk pre-swizzled: chunk = (lane&7)^(lane>>3)  (XOR involution).
  const int srow = lane >> 3;
  const int schunk = (lane & 7) ^ srow;
  const float* gp0 = enc + (rowbase + 0 * 32 + w * 8 + srow) * 1024 + schunk * 4;
  const float* gp1 = enc + (rowbase + 1 * 32 + w * 8 + srow) * 1024 + schunk * 4;
  const float* gp2 = enc + (rowbase + 2 * 32 + w * 8 + srow) * 1024 + schunk * 4;
  const float* gp3 = enc + (rowbase + 3 * 32 + w * 8 + srow) * 1024 + schunk * 4;
  const int l0 = w * 256 + 0 * 1024;   // float offsets within a buffer
  const int l1 = w * 256 + 1 * 1024;
  const int l2 = w * 256 + 2 * 1024;
  const int l3 = w * 256 + 3 * 1024;

  // A-frag read: row = wr*64 + mi*16 + hl; 16B slots (2kg)^(hl&7) and ^1
  const int s0 = ((kg << 1) ^ (hl & 7));
  // B: h = colbase + wc*64 + ni*16 + hl; elem = kb*16384 + h*32 + kg*8
  const short* bp = W2t + (colbase + wc * 64 + hl) * 32 + kg * 8;

  f32x4 acc[4][4];
#pragma unroll
  for (int mi = 0; mi < 4; ++mi)
#pragma unroll
    for (int ni = 0; ni < 4; ++ni) acc[mi][ni] = (f32x4){0.f, 0.f, 0.f, 0.f};

  bf16x8 Ba[4], Bb[4];

#define STAGE(BUF, KB) do {                                   \
    const int _ko = (KB) * 32;                                \
    float* _lb = &As[(BUF)][0];                               \
    GLS16(gp0 + _ko, _lb + l0);                               \
    GLS16(gp1 + _ko, _lb + l1);                               \
    GLS16(gp2 + _ko, _lb + l2);                               \
    GLS16(gp3 + _ko, _lb + l3);                               \
  } while (0)

#define LOADB(DST, KB) do {                                   \
    const short* _bk = bp + (KB) * 16384;                     \
    DST[0] = *reinterpret_cast<const bf16x8*>(_bk);           \
    DST[1] = *reinterpret_cast<const bf16x8*>(_bk + 512);     \
    DST[2] = *reinterpret_cast<const bf16x8*>(_bk + 1024);    \
    DST[3] = *reinterpret_cast<const bf16x8*>(_bk + 1536);    \
  } while (0)

#define COMPUTE(BUF, BREG) do {                                               \
    const float* _ab = &As[(BUF)][0];                                         \
    _Pragma("unroll") for (int mi = 0; mi < 4; ++mi) {                        \
      const int ro = (wr * 64 + mi * 16 + hl) * 32;                           \
      f32x4 lo = *reinterpret_cast<const f32x4*>(_ab + ro + s0 * 4);          \
      f32x4 hi = *reinterpret_cast<const f32x4*>(_ab + ro + (s0 ^ 1) * 4);    \
      union { __bf16 h[8]; bf16x8 s; } u;                                     \
      u.h[0] = (__bf16)lo[0]; u.h[1] = (__bf16)lo[1];                         \
      u.h[2] = (__bf16)lo[2]; u.h[3] = (__bf16)lo[3];                         \
      u.h[4] = (__bf16)hi[0]; u.h[5] = (__bf16)hi[1];                         \
      u.h[6] = (__bf16)hi[2]; u.h[7] = (__bf16)hi[3];                         \
      bf16x8 af = u.s;                                                        \
      acc[mi][0] = __builtin_amdgcn_mfma_f32_16x16x32_bf16(af, BREG[0], acc[mi][0], 0, 0, 0); \
      acc[mi][1] = __builtin_amdgcn_mfma_f32_16x16x32_bf16(af, BREG[1], acc[mi][1], 0, 0, 0); \
      acc[mi][2] = __builtin_amdgcn_mfma_f32_16x16x32_bf16(af, BREG[2], acc[mi][2], 0, 0, 0); \
      acc[mi][3] = __builtin_amdgcn_mfma_f32_16x16x32_bf16(af, BREG[3], acc[mi][3], 0, 0, 0); \
    }                                                                         \
  } while (0)

// one iteration: issue B(KB+1), issue GLS(KB+2), counted wait, barrier, compute
#define ITER(KB, BOUT, BIN, WAITSTR, DOB, DOGLS) do {         \
    if (DOB) LOADB(BOUT, (KB) + 1);                           \
    MEMBAR();                                                 \
    if (DOGLS) STAGE(((KB) + 2) & 3, (KB) + 2);               \
    asm volatile(WAITSTR ::: "memory");                       \
    __builtin_amdgcn_s_barrier();                             \
    MEMBAR();                                                 \
    COMPUTE((KB) & 3, BIN);                                   \
  } while (0)

  // prologue: GLS(0) < B(0) < GLS(1)  (issue-order invariant)
  STAGE(0, 0);
  MEMBAR();
  LOADB(Ba, 0);
  MEMBAR();
  STAGE(1, 1);

  for (int p = 0; p < 15; ++p) {
    const int j = p * 2;
    ITER(j,     Bb, Ba, "s_waitcnt vmcnt(12)", true, true);
    ITER(j + 1, Ba, Bb, "s_waitcnt vmcnt(12)", true, true);
  }
  ITER(30, Bb, Ba, "s_waitcnt vmcnt(8)", true, false);
  ITER(31, Ba, Bb, "s_waitcnt vmcnt(0)", false, false);

#undef STAGE
#undef LOADB
#undef COMPUTE
#undef ITER

  // epilogue: x = acc + P[b][h]; part += v[h]*tanh(x); reduce hl, then wc
  float part[4][4];
#pragma unroll
  for (int mi = 0; mi < 4; ++mi)
#pragma unroll
    for (int r = 0; r < 4; ++r) part[mi][r] = 0.f;

#pragma unroll
  for (int ni = 0; ni < 4; ++ni) {
    const int h = colbase + wc * 64 + ni * 16 + hl;
    const float ph = P[b * 512 + h];
    const float vh = v[h];
#pragma unroll
    for (int mi = 0; mi < 4; ++mi)
#pragma unroll
      for (int r = 0; r < 4; ++r) {
        float x = acc[mi][ni][r] + ph;
        float e = __expf(2.f * x);
        part[mi][r] += vh * (1.f - 2.f * __frcp_rn(e + 1.f));
      }
  }
#pragma unroll
  for (int off = 1; off < 16; off <<= 1)
#pragma unroll
    for (int mi = 0; mi < 4; ++mi)
#pragma unroll
      for (int r = 0; r < 4; ++r)
        part[mi][r] += __shfl_xor(part[mi][r], off, 16);

  __syncthreads();   // K-loop fully done in all waves before attred aliasing
  if (hl == 0) {
#pragma unroll
    for (int mi = 0; mi < 4; ++mi)
#pragma unroll
      for (int r = 0; r < 4; ++r)
        attred[wr * 64 + mi * 16 + kg * 4 + r][wc] = part[mi][r];
  }
  __syncthreads();
  if (tid < 128)
    logits_part[ntile * 65536 + rowbase + tid] = attred[tid][0] + attred[tid][1];
}

// ---- K2: softmax over S=4096 per batch row; input = sum of 4 h-partials
__global__ __launch_bounds__(256) void k_softmax(
    const float* __restrict__ logits_part, float* __restrict__ out) {
  const int b = blockIdx.x;
  const int t = threadIdx.x;
  const int wid = t >> 6, lane = t & 63;
  const float* L0 = logits_part + b * 4096;
  const float* L1 = logits_part + 65536 + b * 4096;
  const float* L2 = logits_part + 131072 + b * 4096;
  const float* L3 = logits_part + 196608 + b * 4096;
  __shared__ float rmax[4], rsum[4];
  float lv[16];
  float m = -1e30f;
#pragma unroll
  for (int i = 0; i < 16; ++i) {
    const int j = t + i * 256;
    lv[i] = (L0[j] + L1[j]) + (L2[j] + L3[j]);
    m = fmaxf(m, lv[i]);
  }
#pragma unroll
  for (int off = 32; off >= 1; off >>= 1) m = fmaxf(m, __shfl_xor(m, off));
  if (lane == 0) rmax[wid] = m;
  __syncthreads();
  m = fmaxf(fmaxf(rmax[0], rmax[1]), fmaxf(rmax[2], rmax[3]));
  float s = 0.f;
#pragma unroll
  for (int i = 0; i < 16; ++i) {
    lv[i] = __expf(lv[i] - m);
    s += lv[i];
  }
#pragma unroll
  for (int off = 32; off >= 1; off >>= 1) s += __shfl_xor(s, off);
  if (lane == 0) rsum[wid] = s;
  __syncthreads();
  s = rsum[0] + rsum[1] + rsum[2] + rsum[3];
  float inv = 1.0f / s;
#pragma unroll
  for (int i = 0; i < 16; ++i) out[b * 4096 + t + i * 256] = lv[i] * inv;
}

extern "C" void kernel_launch(void* const* d_in, const int* in_sizes, int n_in,
                              void* d_out, int out_size, void* d_ws, size_t ws_size,
                              hipStream_t stream) {
  const float* hidden = (const float*)d_in[0];   // [16,512]
  const float* enc    = (const float*)d_in[1];   // [16,4096,1024]
  const float* W      = (const float*)d_in[2];   // [512,1536]
  const float* bias   = (const float*)d_in[3];   // [512]
  const float* v      = (const float*)d_in[4];   // [512]
  float* out = (float*)d_out;                    // [16,4096]

  char* ws = (char*)d_ws;
  float* P = (float*)ws;                                       // 32 KB
  unsigned short* W2t = (unsigned short*)(ws + 32768);         // 1 MB
  float* logits_part = (float*)(ws + 32768 + 1048576);         // 4 x 256 KB

  k_prep_p<<<16, 256, 0, stream>>>(hidden, W, bias, P);
  k_prep_w<<<256, 256, 0, stream>>>(W, W2t);
  k_main<<<2048, 256, 0, stream>>>(enc, (const short*)W2t, P, v, logits_part);
  k_softmax<<<16, 256, 0, stream>>>(logits_part, out);
}